// Round 20
// baseline (138.233 us; speedup 1.0000x reference)
//
#include <hip/hip_runtime.h>
#include <hip/hip_bf16.h>

typedef short bf16x8 __attribute__((ext_vector_type(8)));
typedef float f32x4 __attribute__((ext_vector_type(4)));
typedef unsigned short u16;
typedef unsigned int u32;

__device__ __forceinline__ u16 f2b(float v) {
    u32 u = __float_as_uint(v);
    u += 0x7fff + ((u >> 16) & 1);   // round-to-nearest-even
    return (u16)(u >> 16);
}

__device__ __forceinline__ float b2f(u16 v) {
    return __uint_as_float((u32)v << 16);
}

__device__ __forceinline__ float b2f_lo(u32 v) {
    return __uint_as_float(v << 16);
}

__device__ __forceinline__ float b2f_hi(u32 v) {
    return __uint_as_float(v & 0xffff0000u);
}

__device__ __forceinline__ u32 cvtpk(float lo, float hi) {
    u32 r;
    asm("v_cvt_pk_bf16_f32 %0, %1, %2" : "=v"(r) : "v"(lo), "v"(hi));
    return r;
}

__device__ __forceinline__ void gload16(const void* g, void* l) {
    __builtin_amdgcn_global_load_lds(
        (const __attribute__((address_space(1))) u32*)g,
        (__attribute__((address_space(3))) u32*)l, 16, 0, 0);
}

// ---------------- fused prep: wtq, wtp casts + rpb gather in ONE launch ----------------
// blocks [0,432): wtq[n*192+k] = bf16(qkv_w[k*576+n])
// blocks [432,576): wtp[n*192+k] = bf16(proj_w[k*192+n])
// blocks [576,832): rpb2 bf16 PACKED per attn lane order:
//   rpb2[h][i][c][lg][8]  -> attn lane reads its chunk-c 8 biases as ONE uint4.
__global__ void prep_fused(const float* __restrict__ qkv_w, const float* __restrict__ proj_w,
                           const int* __restrict__ rpi, const float* __restrict__ table,
                           u16* __restrict__ wtq, u16* __restrict__ wtp,
                           u16* __restrict__ rpb2) {
    int b = blockIdx.x;
    if (b < 432) {
        int i = b * 256 + threadIdx.x;
        int n = i / 192, k = i - n * 192;
        wtq[i] = f2b(qkv_w[(size_t)k * 576 + n]);
    } else if (b < 576) {
        int i = (b - 432) * 256 + threadIdx.x;
        int n = i / 192, k = i - n * 192;
        wtp[i] = f2b(proj_w[(size_t)k * 192 + n]);
    } else {
        int ij = (b - 576) * 256 + threadIdx.x;   // i = ij>>8, col = ij&255
        int i = ij >> 8, col = ij & 255;
        int c = col >> 5, r5 = col & 31;
        int lg, e;
        if (r5 < 16) { lg = r5 >> 2; e = r5 & 3; }
        else         { lg = (r5 - 16) >> 2; e = 4 + (r5 & 3); }
        int idx = rpi[ij];
        int dst = i * 256 + c * 32 + lg * 8 + e;
#pragma unroll
        for (int h = 0; h < 6; ++h) rpb2[h * 65536 + dst] = f2b(table[idx * 6 + h]);
    }
}

// ---------------- QKV GEMM: x_f32[65536][192] x Bt[576][192]^T ----------------
__global__ __launch_bounds__(512, 4) void qkv_gemm(const float* __restrict__ A,
                                                   const u16* __restrict__ Bt,
                                                   const float* __restrict__ bias,
                                                   u16* __restrict__ qb, u16* __restrict__ kb,
                                                   u16* __restrict__ vtb, float qscale) {
    __shared__ u16 lsB[2][64 * 192];
    const int m0 = blockIdx.x * 128;
    const int tid = threadIdx.x;
    const int l = tid & 63, wv = tid >> 6;
    const int lr = l & 15, lg = l >> 4;

    bf16x8 areg[6];
    {
        const float* arow = A + (size_t)(m0 + wv * 16 + lr) * 192;
#pragma unroll
        for (int ks = 0; ks < 6; ++ks) {
            float4 a0 = *(const float4*)(arow + ks * 32 + lg * 8);
            float4 a1 = *(const float4*)(arow + ks * 32 + lg * 8 + 4);
            union { u32 u[4]; bf16x8 v; } pk;
            pk.u[0] = cvtpk(a0.x, a0.y);
            pk.u[1] = cvtpk(a0.z, a0.w);
            pk.u[2] = cvtpk(a1.x, a1.y);
            pk.u[3] = cvtpk(a1.z, a1.w);
            areg[ks] = pk.v;
        }
    }

#define STAGE_B(tile, buf)                                                      \
    {                                                                           \
        const u16* src = Bt + (size_t)(tile) * 64 * 192;                        \
        for (int c = tid; c < 1536; c += 512) {                                 \
            int r = c / 24, mc = c - r * 24;                                    \
            int gsw = (mc & ~7) | ((mc ^ r) & 7);                               \
            gload16(src + (r * 24 + gsw) * 8, &lsB[buf][c * 8]);                \
        }                                                                       \
    }
    STAGE_B(0, 0);
    __syncthreads();

    const int wq = m0 >> 8;
    const int ibase = (blockIdx.x & 1) * 128 + wv * 16 + lg * 4;

    for (int n0 = 0; n0 < 9; ++n0) {
        const int cur = n0 & 1;
        if (n0 < 8) STAGE_B(n0 + 1, cur ^ 1);

        f32x4 acc[4] = {};
#pragma unroll
        for (int ks = 0; ks < 6; ++ks) {
            int cidx = ks * 4 + lg;
            int csw = (cidx & ~7) | ((cidx ^ lr) & 7);
#pragma unroll
            for (int bn = 0; bn < 4; ++bn) {
                bf16x8 b = *(const bf16x8*)&lsB[cur][(bn * 16 + lr) * 192 + csw * 8];
                acc[bn] = __builtin_amdgcn_mfma_f32_16x16x32_bf16(areg[ks], b, acc[bn], 0, 0, 0);
            }
        }
        __syncthreads();

        const int mat = n0 / 3;
        const int base = (n0 - mat * 3) * 64;
#pragma unroll
        for (int bn = 0; bn < 4; ++bn) {
            int rem = base + bn * 16 + lr;
            int hh = rem >> 5, dd = rem & 31;
            size_t w6h = (size_t)(wq * 6 + hh);
            float bs = bias[mat * 192 + rem];
            if (mat == 2) {
                int cc = ibase >> 5, col0 = ibase & 31;
                int m2 = ((col0 >> 3) ^ (dd >> 1)) & 3;
                ushort4 st;
                st.x = f2b(acc[bn][0] + bs);
                st.y = f2b(acc[bn][1] + bs);
                st.z = f2b(acc[bn][2] + bs);
                st.w = f2b(acc[bn][3] + bs);
                *(ushort4*)&vtb[w6h * 8192 + cc * 1024 + dd * 32 + (col0 & 7) + m2 * 8] = st;
            } else {
#pragma unroll
                for (int j = 0; j < 4; ++j) {
                    int ii = ibase + j;
                    float v = acc[bn][j] + bs;
                    if (mat == 0) {
                        qb[(w6h * 256 + ii) * 32 + dd] = f2b(v * qscale);
                    } else {
                        int m2 = ((dd >> 3) ^ (ii >> 1)) & 3;
                        kb[w6h * 8192 + ii * 32 + (dd & 7) + m2 * 8] = f2b(v);
                    }
                }
            }
        }
    }
}

// ---------------- proj GEMM: out[65536][192] = ob[65536][192] x wtp[192][192]^T ----
__global__ __launch_bounds__(512, 4) void proj_gemm(const u16* __restrict__ A,
                                                    const u16* __restrict__ Bt,
                                                    const float* __restrict__ bias,
                                                    float* __restrict__ out) {
    __shared__ u16 lsB[192 * 192];
    const int m0 = blockIdx.x * 128;
    const int tid = threadIdx.x;
    const int l = tid & 63, wv = tid >> 6;
    const int lr = l & 15, lg = l >> 4;

    for (int c = tid; c < 4608; c += 512) {
        int r = c / 24, mc = c - r * 24;
        int gsw = (mc & ~7) | ((mc ^ r) & 7);
        gload16(Bt + (r * 24 + gsw) * 8, &lsB[c * 8]);
    }

    bf16x8 areg[6];
    {
        const u16* arow = A + (size_t)(m0 + wv * 16 + lr) * 192;
#pragma unroll
        for (int ks = 0; ks < 6; ++ks)
            areg[ks] = *(const bf16x8*)(arow + ks * 32 + lg * 8);
    }
    __syncthreads();

#pragma unroll
    for (int t = 0; t < 3; ++t) {
        f32x4 acc[4] = {};
#pragma unroll
        for (int ks = 0; ks < 6; ++ks) {
            int cidx = ks * 4 + lg;
            int csw = (cidx & ~7) | ((cidx ^ lr) & 7);
#pragma unroll
            for (int bn = 0; bn < 4; ++bn) {
                bf16x8 b = *(const bf16x8*)&lsB[(t * 64 + bn * 16 + lr) * 192 + csw * 8];
                acc[bn] = __builtin_amdgcn_mfma_f32_16x16x32_bf16(areg[ks], b, acc[bn], 0, 0, 0);
            }
        }
#pragma unroll
        for (int bn = 0; bn < 4; ++bn)
#pragma unroll
            for (int j = 0; j < 4; ++j) {
                int gr = m0 + wv * 16 + lg * 4 + j;
                int gc = t * 64 + bn * 16 + lr;
                out[(size_t)gr * 192 + gc] = acc[bn][j] + bias[gc];
            }
    }
}

// ---------------- attention ----------------
// r20 = r19 attn with BIAS FUSION at head start: load mask (16 float4) +
// rpb2 (8 uint4) once per head, pre-sum and pack to 32 persistent u32s
// (bf16 pairs). The chunk loop then has ZERO global loads — chain is
// ds_read -> MFMA -> reg-add -> exp -> pack -> lp -> PV. 32 bias regs is
// HALF the old f32 burst footprint -> fits the compiler's 64-VGPR pin
// (r18 showed 64-reg f32 bursts get re-sunk). One add/value replaces two.
// Everything else byte-identical to the 6x-passed structure.
__global__ __launch_bounds__(512, 4) void attn_k(const u16* __restrict__ qb,
                                                 const u16* __restrict__ kb,
                                                 const u16* __restrict__ vtb,
                                                 const u16* __restrict__ rpb2,
                                                 const float* __restrict__ mask,
                                                 u16* __restrict__ out) {
    __shared__ u16 lk[2][8192];    // K head rows (swizzled content, linear layout)
    __shared__ u16 lvt[2][8192];   // V^T head, chunk-major (swizzled content)
    __shared__ u16 lp[8 * 640];    // per-wave P scratch [16 q][40]

    const int bid = blockIdx.x;
    const int xcd = bid & 7, idx = bid >> 3;
    const int w = xcd * 32 + (idx >> 1), half = idx & 1;
    const int tid = threadIdx.x;
    const int l = tid & 63, wv = tid >> 6;
    const int lr = l & 15, lg = l >> 4;
    const int qrow = half * 128 + wv * 16 + lr;

#define STAGE_KV(hh, buf)                                                        \
    {                                                                            \
        const u16* ks = kb + (size_t)(w * 6 + (hh)) * 8192;                      \
        const u16* vs = vtb + (size_t)(w * 6 + (hh)) * 8192;                     \
        for (int c = tid; c < 1024; c += 512) {                                  \
            gload16(ks + c * 8, &lk[buf][c * 8]);                                \
            gload16(vs + c * 8, &lvt[buf][c * 8]);                               \
        }                                                                        \
    }

    STAGE_KV(0, 0);
    bf16x8 bq_n = *(const bf16x8*)(qb + ((size_t)(w * 6 + 0) * 256 + qrow) * 32 + lg * 8);
    __syncthreads();  // head 0 staged

    const float* mrow = mask + (size_t)w * 65536 + (size_t)qrow * 256;
    u16* pb = lp + wv * 640;
    const int koff = lr * 32 + (lg ^ ((lr >> 1) & 3)) * 8;  // swizzled read offset

    for (int h = 0; h < 6; ++h) {
        const int cur = h & 1, nxt = cur ^ 1;
        if (h < 5) STAGE_KV(h + 1, nxt);
        bf16x8 bq = bq_n;
        if (h < 5)
            bq_n = *(const bf16x8*)(qb + ((size_t)(w * 6 + h + 1) * 256 + qrow) * 32 + lg * 8);

        const u16* brow = rpb2 + (size_t)h * 65536 + (size_t)qrow * 256;

        // bias fusion: mask + rpb pre-summed, packed bf16, 32 persistent u32s
        u32 biasw[32];
#pragma unroll
        for (int c = 0; c < 8; ++c) {
            float4 m0 = *(const float4*)(mrow + c * 32 + lg * 4);
            float4 m1 = *(const float4*)(mrow + c * 32 + 16 + lg * 4);
            union { uint4 q; u16 s[8]; } bu;
            bu.q = *(const uint4*)(brow + c * 32 + lg * 8);
            biasw[4 * c + 0] = cvtpk(m0.x + b2f(bu.s[0]), m0.y + b2f(bu.s[1]));
            biasw[4 * c + 1] = cvtpk(m0.z + b2f(bu.s[2]), m0.w + b2f(bu.s[3]));
            biasw[4 * c + 2] = cvtpk(m1.x + b2f(bu.s[4]), m1.y + b2f(bu.s[5]));
            biasw[4 * c + 3] = cvtpk(m1.z + b2f(bu.s[6]), m1.w + b2f(bu.s[7]));
        }

        const f32x4 zero = {0.f, 0.f, 0.f, 0.f};
        f32x4 o[2] = {};
        float sum = 0.f;

#pragma unroll
        for (int c = 0; c < 8; ++c) {
            // QK^T for 32 kv cols
            bf16x8 ak0 = *(const bf16x8*)&lk[cur][(2 * c) * 512 + koff];
            bf16x8 ak1 = *(const bf16x8*)&lk[cur][(2 * c + 1) * 512 + koff];
            f32x4 s0 = __builtin_amdgcn_mfma_f32_16x16x32_bf16(ak0, bq, zero, 0, 0, 0);
            f32x4 s1 = __builtin_amdgcn_mfma_f32_16x16x32_bf16(ak1, bq, zero, 0, 0, 0);

            // bias from registers only — no memory on the chain
            s0[0] = __expf(s0[0] + b2f_lo(biasw[4 * c + 0]));
            s0[1] = __expf(s0[1] + b2f_hi(biasw[4 * c + 0]));
            s0[2] = __expf(s0[2] + b2f_lo(biasw[4 * c + 1]));
            s0[3] = __expf(s0[3] + b2f_hi(biasw[4 * c + 1]));
            s1[0] = __expf(s1[0] + b2f_lo(biasw[4 * c + 2]));
            s1[1] = __expf(s1[1] + b2f_hi(biasw[4 * c + 2]));
            s1[2] = __expf(s1[2] + b2f_lo(biasw[4 * c + 3]));
            s1[3] = __expf(s1[3] + b2f_hi(biasw[4 * c + 3]));
            sum += ((s0[0] + s0[1]) + (s0[2] + s0[3])) + ((s1[0] + s1[1]) + (s1[2] + s1[3]));

            uint2 w0, w1;
            w0.x = cvtpk(s0[0], s0[1]); w0.y = cvtpk(s0[2], s0[3]);
            w1.x = cvtpk(s1[0], s1[1]); w1.y = cvtpk(s1[2], s1[3]);
            *(uint2*)&pb[lr * 40 + lg * 4] = w0;
            *(uint2*)&pb[lr * 40 + 16 + lg * 4] = w1;

            bf16x8 ap = *(const bf16x8*)&pb[lr * 40 + lg * 8];
            bf16x8 v0 = *(const bf16x8*)&lvt[cur][c * 1024 + koff];
            bf16x8 v1 = *(const bf16x8*)&lvt[cur][c * 1024 + 512 + koff];
            o[0] = __builtin_amdgcn_mfma_f32_16x16x32_bf16(ap, v0, o[0], 0, 0, 0);
            o[1] = __builtin_amdgcn_mfma_f32_16x16x32_bf16(ap, v1, o[1], 0, 0, 0);
        }

        sum += __shfl_xor(sum, 16);
        sum += __shfl_xor(sum, 32);
        float rinv[4];
#pragma unroll
        for (int j = 0; j < 4; ++j) rinv[j] = __builtin_amdgcn_rcpf(__shfl(sum, lg * 4 + j));
#pragma unroll
        for (int dt = 0; dt < 2; ++dt)
#pragma unroll
            for (int j = 0; j < 4; ++j) {
                int i = half * 128 + wv * 16 + lg * 4 + j;
                out[((size_t)(w * 256 + i)) * 192 + h * 32 + dt * 16 + lr] =
                    f2b(o[dt][j] * rinv[j]);
            }
        __syncthreads();  // next-head staging landed; cur buffers free
    }
}

extern "C" void kernel_launch(void* const* d_in, const int* in_sizes, int n_in,
                              void* d_out, int out_size, void* d_ws, size_t ws_size,
                              hipStream_t stream) {
    const float* x      = (const float*)d_in[0];
    const int*   rpi    = (const int*)d_in[1];
    const float* mask   = (const float*)d_in[2];
    const float* qkv_w  = (const float*)d_in[3];
    const float* qkv_b  = (const float*)d_in[4];
    const float* proj_w = (const float*)d_in[5];
    const float* proj_b = (const float*)d_in[6];
    const float* table  = (const float*)d_in[7];

    char* p = (char*)d_ws;
    u16* ob   = (u16*)p;  p += (size_t)65536 * 192 * 2;  // attn output bf16
    u16* qb   = (u16*)p;  p += (size_t)65536 * 192 * 2;  // Q  [w][h][i][d] bf16 (pre-scaled)
    u16* kb   = (u16*)p;  p += (size_t)65536 * 192 * 2;  // K  [w][h][i][d'] bf16 (swizzled)
    u16* vtb  = (u16*)p;  p += (size_t)65536 * 192 * 2;  // V^T [w][h][c][d][col'] (swizzled)
    u16* wtq  = (u16*)p;  p += (size_t)576 * 192 * 2;    // qkv_w^T bf16
    u16* wtp  = (u16*)p;  p += (size_t)192 * 192 * 2;    // proj_w^T bf16
    u16* rpb2 = (u16*)p;  p += (size_t)6 * 65536 * 2;    // packed bf16 [6][i][c][lg][8]

    hipLaunchKernelGGL(prep_fused, dim3(832), dim3(256), 0, stream,
                       qkv_w, proj_w, rpi, table, wtq, wtp, rpb2);

    const float qscale = 0.17677669529663687f;  // 1/sqrt(32)
    hipLaunchKernelGGL(qkv_gemm, dim3(512), dim3(512), 0, stream,
                       x, wtq, qkv_b, qb, kb, vtb, qscale);
    hipLaunchKernelGGL(attn_k, dim3(512), dim3(512), 0, stream, qb, kb, vtb, rpb2, mask, ob);
    hipLaunchKernelGGL(proj_gemm, dim3(512), dim3(512), 0, stream,
                       ob, wtp, proj_b, (float*)d_out);
}

// Round 21
// 111.375 us; speedup vs baseline: 1.2411x; 1.2411x over previous
//
#include <hip/hip_runtime.h>
#include <hip/hip_bf16.h>

typedef short bf16x8 __attribute__((ext_vector_type(8)));
typedef float f32x4 __attribute__((ext_vector_type(4)));
typedef unsigned short u16;
typedef unsigned int u32;

__device__ __forceinline__ u16 f2b(float v) {
    u32 u = __float_as_uint(v);
    u += 0x7fff + ((u >> 16) & 1);   // round-to-nearest-even
    return (u16)(u >> 16);
}

__device__ __forceinline__ float b2f(u16 v) {
    return __uint_as_float((u32)v << 16);
}

__device__ __forceinline__ u32 cvtpk(float lo, float hi) {
    u32 r;
    asm("v_cvt_pk_bf16_f32 %0, %1, %2" : "=v"(r) : "v"(lo), "v"(hi));
    return r;
}

__device__ __forceinline__ void gload16(const void* g, void* l) {
    __builtin_amdgcn_global_load_lds(
        (const __attribute__((address_space(1))) u32*)g,
        (__attribute__((address_space(3))) u32*)l, 16, 0, 0);
}

// ---------------- fused prep: wtq, wtp casts + rpb gather in ONE launch ----------------
// blocks [0,432): wtq[n*192+k] = bf16(qkv_w[k*576+n])
// blocks [432,576): wtp[n*192+k] = bf16(proj_w[k*192+n])
// blocks [576,832): rpb2 bf16 PACKED per attn lane order:
//   rpb2[h][i][c][lg][8]  -> attn lane reads its chunk-c 8 biases as ONE uint4.
__global__ void prep_fused(const float* __restrict__ qkv_w, const float* __restrict__ proj_w,
                           const int* __restrict__ rpi, const float* __restrict__ table,
                           u16* __restrict__ wtq, u16* __restrict__ wtp,
                           u16* __restrict__ rpb2) {
    int b = blockIdx.x;
    if (b < 432) {
        int i = b * 256 + threadIdx.x;
        int n = i / 192, k = i - n * 192;
        wtq[i] = f2b(qkv_w[(size_t)k * 576 + n]);
    } else if (b < 576) {
        int i = (b - 432) * 256 + threadIdx.x;
        int n = i / 192, k = i - n * 192;
        wtp[i] = f2b(proj_w[(size_t)k * 192 + n]);
    } else {
        int ij = (b - 576) * 256 + threadIdx.x;   // i = ij>>8, col = ij&255
        int i = ij >> 8, col = ij & 255;
        int c = col >> 5, r5 = col & 31;
        int lg, e;
        if (r5 < 16) { lg = r5 >> 2; e = r5 & 3; }
        else         { lg = (r5 - 16) >> 2; e = 4 + (r5 & 3); }
        int idx = rpi[ij];
        int dst = i * 256 + c * 32 + lg * 8 + e;
#pragma unroll
        for (int h = 0; h < 6; ++h) rpb2[h * 65536 + dst] = f2b(table[idx * 6 + h]);
    }
}

// ---------------- QKV GEMM: x_f32[65536][192] x Bt[576][192]^T ----------------
// BM=128 (512 blocks), A read DIRECTLY from f32 x (cvt_pk in kernel), wave owns
// 16 rows in registers; 9 N-tiles of 64 cols, double-buffered async B staging.
// Epilogue writes K and V^T PRE-SWIZZLED; V^T uses ushort4 stores.
__global__ __launch_bounds__(512, 4) void qkv_gemm(const float* __restrict__ A,
                                                   const u16* __restrict__ Bt,
                                                   const float* __restrict__ bias,
                                                   u16* __restrict__ qb, u16* __restrict__ kb,
                                                   u16* __restrict__ vtb, float qscale) {
    __shared__ u16 lsB[2][64 * 192];
    const int m0 = blockIdx.x * 128;
    const int tid = threadIdx.x;
    const int l = tid & 63, wv = tid >> 6;
    const int lr = l & 15, lg = l >> 4;

    bf16x8 areg[6];
    {
        const float* arow = A + (size_t)(m0 + wv * 16 + lr) * 192;
#pragma unroll
        for (int ks = 0; ks < 6; ++ks) {
            float4 a0 = *(const float4*)(arow + ks * 32 + lg * 8);
            float4 a1 = *(const float4*)(arow + ks * 32 + lg * 8 + 4);
            union { u32 u[4]; bf16x8 v; } pk;
            pk.u[0] = cvtpk(a0.x, a0.y);
            pk.u[1] = cvtpk(a0.z, a0.w);
            pk.u[2] = cvtpk(a1.x, a1.y);
            pk.u[3] = cvtpk(a1.z, a1.w);
            areg[ks] = pk.v;
        }
    }

#define STAGE_B(tile, buf)                                                      \
    {                                                                           \
        const u16* src = Bt + (size_t)(tile) * 64 * 192;                        \
        for (int c = tid; c < 1536; c += 512) {                                 \
            int r = c / 24, mc = c - r * 24;                                    \
            int gsw = (mc & ~7) | ((mc ^ r) & 7);                               \
            gload16(src + (r * 24 + gsw) * 8, &lsB[buf][c * 8]);                \
        }                                                                       \
    }
    STAGE_B(0, 0);
    __syncthreads();

    const int wq = m0 >> 8;
    const int ibase = (blockIdx.x & 1) * 128 + wv * 16 + lg * 4;

    for (int n0 = 0; n0 < 9; ++n0) {
        const int cur = n0 & 1;
        if (n0 < 8) STAGE_B(n0 + 1, cur ^ 1);

        f32x4 acc[4] = {};
#pragma unroll
        for (int ks = 0; ks < 6; ++ks) {
            int cidx = ks * 4 + lg;
            int csw = (cidx & ~7) | ((cidx ^ lr) & 7);
#pragma unroll
            for (int bn = 0; bn < 4; ++bn) {
                bf16x8 b = *(const bf16x8*)&lsB[cur][(bn * 16 + lr) * 192 + csw * 8];
                acc[bn] = __builtin_amdgcn_mfma_f32_16x16x32_bf16(areg[ks], b, acc[bn], 0, 0, 0);
            }
        }
        __syncthreads();

        const int mat = n0 / 3;
        const int base = (n0 - mat * 3) * 64;
#pragma unroll
        for (int bn = 0; bn < 4; ++bn) {
            int rem = base + bn * 16 + lr;
            int hh = rem >> 5, dd = rem & 31;
            size_t w6h = (size_t)(wq * 6 + hh);
            float bs = bias[mat * 192 + rem];
            if (mat == 2) {
                // 4 consecutive u16 -> one ushort4 store
                int cc = ibase >> 5, col0 = ibase & 31;
                int m2 = ((col0 >> 3) ^ (dd >> 1)) & 3;
                ushort4 st;
                st.x = f2b(acc[bn][0] + bs);
                st.y = f2b(acc[bn][1] + bs);
                st.z = f2b(acc[bn][2] + bs);
                st.w = f2b(acc[bn][3] + bs);
                *(ushort4*)&vtb[w6h * 8192 + cc * 1024 + dd * 32 + (col0 & 7) + m2 * 8] = st;
            } else {
#pragma unroll
                for (int j = 0; j < 4; ++j) {
                    int ii = ibase + j;
                    float v = acc[bn][j] + bs;
                    if (mat == 0) {
                        qb[(w6h * 256 + ii) * 32 + dd] = f2b(v * qscale);
                    } else {
                        int m2 = ((dd >> 3) ^ (ii >> 1)) & 3;
                        kb[w6h * 8192 + ii * 32 + (dd & 7) + m2 * 8] = f2b(v);
                    }
                }
            }
        }
    }
}

// ---------------- proj GEMM: out[65536][192] = ob[65536][192] x wtp[192][192]^T ----
__global__ __launch_bounds__(512, 4) void proj_gemm(const u16* __restrict__ A,
                                                    const u16* __restrict__ Bt,
                                                    const float* __restrict__ bias,
                                                    float* __restrict__ out) {
    __shared__ u16 lsB[192 * 192];
    const int m0 = blockIdx.x * 128;
    const int tid = threadIdx.x;
    const int l = tid & 63, wv = tid >> 6;
    const int lr = l & 15, lg = l >> 4;

    for (int c = tid; c < 4608; c += 512) {
        int r = c / 24, mc = c - r * 24;
        int gsw = (mc & ~7) | ((mc ^ r) & 7);
        gload16(Bt + (r * 24 + gsw) * 8, &lsB[c * 8]);
    }

    bf16x8 areg[6];
    {
        const u16* arow = A + (size_t)(m0 + wv * 16 + lr) * 192;
#pragma unroll
        for (int ks = 0; ks < 6; ++ks)
            areg[ks] = *(const bf16x8*)(arow + ks * 32 + lg * 8);
    }
    __syncthreads();

#pragma unroll
    for (int t = 0; t < 3; ++t) {
        f32x4 acc[4] = {};
#pragma unroll
        for (int ks = 0; ks < 6; ++ks) {
            int cidx = ks * 4 + lg;
            int csw = (cidx & ~7) | ((cidx ^ lr) & 7);
#pragma unroll
            for (int bn = 0; bn < 4; ++bn) {
                bf16x8 b = *(const bf16x8*)&lsB[(t * 64 + bn * 16 + lr) * 192 + csw * 8];
                acc[bn] = __builtin_amdgcn_mfma_f32_16x16x32_bf16(areg[ks], b, acc[bn], 0, 0, 0);
            }
        }
#pragma unroll
        for (int bn = 0; bn < 4; ++bn)
#pragma unroll
            for (int j = 0; j < 4; ++j) {
                int gr = m0 + wv * 16 + lg * 4 + j;
                int gc = t * 64 + bn * 16 + lr;
                out[(size_t)gr * 192 + gc] = acc[bn][j] + bias[gc];
            }
    }
}

// ---------------- attention ----------------
// r21 = r19 attn VERBATIM (66.4 us, best measured). Per-chunk loads: 2x mask
// float4 + ONE packed-bf16 rpb2 uint4 (lane-order packed by prep). r20's
// bias-fusion attempt proved (4th time) that the allocator pins ~52-64 VGPRs
// and REMATERIALIZES any larger persistent state from global (FETCH 3x).
// Structure: block = (window, q-half), 8 waves x 16 q-rows, 6-head loop,
// double-buffered K/V DMA staging (pre-swizzled), per-wave LDS P-transpose,
// streaming no-max softmax.
__global__ __launch_bounds__(512, 4) void attn_k(const u16* __restrict__ qb,
                                                 const u16* __restrict__ kb,
                                                 const u16* __restrict__ vtb,
                                                 const u16* __restrict__ rpb2,
                                                 const float* __restrict__ mask,
                                                 u16* __restrict__ out) {
    __shared__ u16 lk[2][8192];    // K head rows (swizzled content, linear layout)
    __shared__ u16 lvt[2][8192];   // V^T head, chunk-major (swizzled content)
    __shared__ u16 lp[8 * 640];    // per-wave P scratch [16 q][40]

    const int bid = blockIdx.x;
    const int xcd = bid & 7, idx = bid >> 3;
    const int w = xcd * 32 + (idx >> 1), half = idx & 1;
    const int tid = threadIdx.x;
    const int l = tid & 63, wv = tid >> 6;
    const int lr = l & 15, lg = l >> 4;
    const int qrow = half * 128 + wv * 16 + lr;

#define STAGE_KV(hh, buf)                                                        \
    {                                                                            \
        const u16* ks = kb + (size_t)(w * 6 + (hh)) * 8192;                      \
        const u16* vs = vtb + (size_t)(w * 6 + (hh)) * 8192;                     \
        for (int c = tid; c < 1024; c += 512) {                                  \
            gload16(ks + c * 8, &lk[buf][c * 8]);                                \
            gload16(vs + c * 8, &lvt[buf][c * 8]);                               \
        }                                                                        \
    }

    STAGE_KV(0, 0);
    bf16x8 bq_n = *(const bf16x8*)(qb + ((size_t)(w * 6 + 0) * 256 + qrow) * 32 + lg * 8);
    __syncthreads();  // head 0 staged

    const float* mrow = mask + (size_t)w * 65536 + (size_t)qrow * 256;
    u16* pb = lp + wv * 640;
    const int koff = lr * 32 + (lg ^ ((lr >> 1) & 3)) * 8;  // swizzled read offset

    for (int h = 0; h < 6; ++h) {
        const int cur = h & 1, nxt = cur ^ 1;
        if (h < 5) STAGE_KV(h + 1, nxt);
        bf16x8 bq = bq_n;
        if (h < 5)
            bq_n = *(const bf16x8*)(qb + ((size_t)(w * 6 + h + 1) * 256 + qrow) * 32 + lg * 8);

        const u16* brow = rpb2 + (size_t)h * 65536 + (size_t)qrow * 256;

        // burst: issue the whole head's mask loads (16 x float4, 8-deep MLP)
        float4 mv[16];
#pragma unroll
        for (int c = 0; c < 8; ++c) {
            mv[2 * c]     = *(const float4*)(mrow + c * 32 + lg * 4);
            mv[2 * c + 1] = *(const float4*)(mrow + c * 32 + 16 + lg * 4);
        }

        const f32x4 zero = {0.f, 0.f, 0.f, 0.f};
        f32x4 o[2] = {};
        float sum = 0.f;

#pragma unroll
        for (int c = 0; c < 8; ++c) {
            // QK^T for 32 kv cols
            bf16x8 ak0 = *(const bf16x8*)&lk[cur][(2 * c) * 512 + koff];
            bf16x8 ak1 = *(const bf16x8*)&lk[cur][(2 * c + 1) * 512 + koff];
            f32x4 s0 = __builtin_amdgcn_mfma_f32_16x16x32_bf16(ak0, bq, zero, 0, 0, 0);
            f32x4 s1 = __builtin_amdgcn_mfma_f32_16x16x32_bf16(ak1, bq, zero, 0, 0, 0);

            // rpb: ONE packed-bf16 uint4 for all 8 biases of this chunk
            union { uint4 q; u16 s[8]; } bvu;
            bvu.q = *(const uint4*)(brow + c * 32 + lg * 8);

            s0[0] = __expf(s0[0] + mv[2 * c].x + b2f(bvu.s[0]));
            s0[1] = __expf(s0[1] + mv[2 * c].y + b2f(bvu.s[1]));
            s0[2] = __expf(s0[2] + mv[2 * c].z + b2f(bvu.s[2]));
            s0[3] = __expf(s0[3] + mv[2 * c].w + b2f(bvu.s[3]));
            s1[0] = __expf(s1[0] + mv[2 * c + 1].x + b2f(bvu.s[4]));
            s1[1] = __expf(s1[1] + mv[2 * c + 1].y + b2f(bvu.s[5]));
            s1[2] = __expf(s1[2] + mv[2 * c + 1].z + b2f(bvu.s[6]));
            s1[3] = __expf(s1[3] + mv[2 * c + 1].w + b2f(bvu.s[7]));
            sum += ((s0[0] + s0[1]) + (s0[2] + s0[3])) + ((s1[0] + s1[1]) + (s1[2] + s1[3]));

            uint2 w0, w1;
            w0.x = cvtpk(s0[0], s0[1]); w0.y = cvtpk(s0[2], s0[3]);
            w1.x = cvtpk(s1[0], s1[1]); w1.y = cvtpk(s1[2], s1[3]);
            *(uint2*)&pb[lr * 40 + lg * 4] = w0;
            *(uint2*)&pb[lr * 40 + 16 + lg * 4] = w1;

            bf16x8 ap = *(const bf16x8*)&pb[lr * 40 + lg * 8];
            bf16x8 v0 = *(const bf16x8*)&lvt[cur][c * 1024 + koff];
            bf16x8 v1 = *(const bf16x8*)&lvt[cur][c * 1024 + 512 + koff];
            o[0] = __builtin_amdgcn_mfma_f32_16x16x32_bf16(ap, v0, o[0], 0, 0, 0);
            o[1] = __builtin_amdgcn_mfma_f32_16x16x32_bf16(ap, v1, o[1], 0, 0, 0);
        }

        sum += __shfl_xor(sum, 16);
        sum += __shfl_xor(sum, 32);
        float rinv[4];
#pragma unroll
        for (int j = 0; j < 4; ++j) rinv[j] = __builtin_amdgcn_rcpf(__shfl(sum, lg * 4 + j));
#pragma unroll
        for (int dt = 0; dt < 2; ++dt)
#pragma unroll
            for (int j = 0; j < 4; ++j) {
                int i = half * 128 + wv * 16 + lg * 4 + j;
                out[((size_t)(w * 256 + i)) * 192 + h * 32 + dt * 16 + lr] =
                    f2b(o[dt][j] * rinv[j]);
            }
        __syncthreads();  // next-head staging landed; cur buffers free
    }
}

extern "C" void kernel_launch(void* const* d_in, const int* in_sizes, int n_in,
                              void* d_out, int out_size, void* d_ws, size_t ws_size,
                              hipStream_t stream) {
    const float* x      = (const float*)d_in[0];
    const int*   rpi    = (const int*)d_in[1];
    const float* mask   = (const float*)d_in[2];
    const float* qkv_w  = (const float*)d_in[3];
    const float* qkv_b  = (const float*)d_in[4];
    const float* proj_w = (const float*)d_in[5];
    const float* proj_b = (const float*)d_in[6];
    const float* table  = (const float*)d_in[7];

    char* p = (char*)d_ws;
    u16* ob   = (u16*)p;  p += (size_t)65536 * 192 * 2;  // attn output bf16
    u16* qb   = (u16*)p;  p += (size_t)65536 * 192 * 2;  // Q  [w][h][i][d] bf16 (pre-scaled)
    u16* kb   = (u16*)p;  p += (size_t)65536 * 192 * 2;  // K  [w][h][i][d'] bf16 (swizzled)
    u16* vtb  = (u16*)p;  p += (size_t)65536 * 192 * 2;  // V^T [w][h][c][d][col'] (swizzled)
    u16* wtq  = (u16*)p;  p += (size_t)576 * 192 * 2;    // qkv_w^T bf16
    u16* wtp  = (u16*)p;  p += (size_t)192 * 192 * 2;    // proj_w^T bf16
    u16* rpb2 = (u16*)p;  p += (size_t)6 * 65536 * 2;    // packed bf16 [6][i][c][lg][8]

    hipLaunchKernelGGL(prep_fused, dim3(832), dim3(256), 0, stream,
                       qkv_w, proj_w, rpi, table, wtq, wtp, rpb2);

    const float qscale = 0.17677669529663687f;  // 1/sqrt(32)
    hipLaunchKernelGGL(qkv_gemm, dim3(512), dim3(512), 0, stream,
                       x, wtq, qkv_b, qb, kb, vtb, qscale);
    hipLaunchKernelGGL(attn_k, dim3(512), dim3(512), 0, stream, qb, kb, vtb, rpb2, mask, ob);
    hipLaunchKernelGGL(proj_gemm, dim3(512), dim3(512), 0, stream,
                       ob, wtp, proj_b, (float*)d_out);
}